// Round 1
// baseline (4990.668 us; speedup 1.0000x reference)
//
#include <hip/hip_runtime.h>

#define N_NODES 50000
#define S_NEI 16
#define E_EDGES 400000
#define DDIM 128
#define EDIMC 64
#define NHEAD 4
#define KHEAD 32
#define NMPC 2
#define DEPTHC 2

__device__ __forceinline__ unsigned short f2bf(float f) {
  unsigned int u = __float_as_uint(f);
  unsigned int r = (u + 0x7fffu + ((u >> 16) & 1u)) >> 16;
  return (unsigned short)r;
}
__device__ __forceinline__ float bflo(unsigned int u) { return __uint_as_float(u << 16); }
__device__ __forceinline__ float bfhi(unsigned int u) { return __uint_as_float(u & 0xffff0000u); }

// Y[M,128] = X[M,KDIM] @ W ; W layout: HDK ? [H=4][KDIM][32] (col c = h*32+k) : [KDIM][128]
// OUTBF16: store bf16 (RNE), else f32.
template<int KDIM, bool HDK, bool OUTBF16>
__global__ __launch_bounds__(512)
void gemm_k(const float* __restrict__ X, const float* __restrict__ W,
            void* __restrict__ Yv, int M) {
  static_assert(!HDK || KDIM == 128, "HDK remap assumes KDIM=128");
  __shared__ float Wl[KDIM * 128];
  __shared__ float At[KDIM * 68];   // A-tile transposed: [k][row], pad 68 (16B-aligned rows, bank spread)
  const int tid = threadIdx.x;

  // Stage W into LDS in [k][c] layout
  for (int lin = tid; lin < KDIM * 128; lin += 512) {
    int k, c;
    if (HDK) {
      int h = lin >> 12, d = (lin >> 5) & 127, kk = lin & 31;
      k = d; c = (h << 5) | kk;
    } else {
      k = lin >> 7; c = lin & 127;
    }
    Wl[k * 128 + c] = W[lin];
  }

  // Stage 64-row A tile (transposed)
  const long tile0 = (long)blockIdx.x * 64;
  const float4* X4 = (const float4*)X;
  const int nvec = 64 * KDIM / 4;
  for (int i = tid; i < nvec; i += 512) {
    int r = i / (KDIM / 4);
    int c4 = i % (KDIM / 4);
    long row = tile0 + r; if (row >= M) row = M - 1;   // clamp; guarded on store
    float4 a = X4[row * (KDIM / 4) + c4];
    int k0 = c4 * 4;
    At[(k0 + 0) * 68 + r] = a.x;
    At[(k0 + 1) * 68 + r] = a.y;
    At[(k0 + 2) * 68 + r] = a.z;
    At[(k0 + 3) * 68 + r] = a.w;
  }
  __syncthreads();

  const int c4 = (tid & 31) << 2;   // 4 cols starting here
  const int rg = (tid >> 5) << 2;   // 4 rows starting here
  float acc[4][4] = {};

  #pragma unroll 4
  for (int k = 0; k < KDIM; ++k) {
    const float4 b = *(const float4*)(Wl + k * 128 + c4);
    const float4 a = *(const float4*)(At + k * 68 + rg);
    const float av[4] = {a.x, a.y, a.z, a.w};
    const float bv[4] = {b.x, b.y, b.z, b.w};
    #pragma unroll
    for (int i = 0; i < 4; ++i)
      #pragma unroll
      for (int j = 0; j < 4; ++j)
        acc[i][j] = fmaf(av[i], bv[j], acc[i][j]);
  }

  const long row0 = tile0 + rg;
  if (OUTBF16) {
    unsigned short* Y = (unsigned short*)Yv;
    #pragma unroll
    for (int i = 0; i < 4; ++i) {
      long r = row0 + i;
      if (r < M) {
        ushort4 o;
        o.x = f2bf(acc[i][0]); o.y = f2bf(acc[i][1]);
        o.z = f2bf(acc[i][2]); o.w = f2bf(acc[i][3]);
        *(ushort4*)(Y + r * 128 + c4) = o;
      }
    }
  } else {
    float* Y = (float*)Yv;
    #pragma unroll
    for (int i = 0; i < 4; ++i) {
      long r = row0 + i;
      if (r < M) {
        float4 o; o.x = acc[i][0]; o.y = acc[i][1]; o.z = acc[i][2]; o.w = acc[i][3];
        *(float4*)(Y + r * 128 + c4) = o;
      }
    }
  }
}

// One wave per edge. s=2 endpoints. Q/K/V bf16 (2 cols per lane). Writes f32 edges in place.
__global__ __launch_bounds__(256)
void edge_attn(const unsigned int* __restrict__ Qe, const unsigned int* __restrict__ Kn,
               const unsigned int* __restrict__ Vn, const int* __restrict__ adj,
               float* __restrict__ edges) {
  const int lane = threadIdx.x & 63;
  const long e = (long)blockIdx.x * 4 + (threadIdx.x >> 6);
  const unsigned int q = Qe[e * 64 + lane];
  const int n0 = adj[e * 2 + 0];
  const int n1 = adj[e * 2 + 1];
  const unsigned int k0 = Kn[(long)n0 * 64 + lane];
  const unsigned int k1 = Kn[(long)n1 * 64 + lane];
  const unsigned int v0 = Vn[(long)n0 * 64 + lane];
  const unsigned int v1 = Vn[(long)n1 * 64 + lane];
  const float qa = bflo(q), qb = bfhi(q);
  float p0 = qa * bflo(k0) + qb * bfhi(k0);
  float p1 = qa * bflo(k1) + qb * bfhi(k1);
  #pragma unroll
  for (int off = 1; off < 16; off <<= 1) {
    p0 += __shfl_xor(p0, off);
    p1 += __shfl_xor(p1, off);
  }
  const float scale = 0.17677669529663687f;  // 1/sqrt(32)
  const float s0 = p0 * scale, s1 = p1 * scale;
  const float m = fmaxf(s0, s1);
  const float e0 = __expf(s0 - m), e1 = __expf(s1 - m);
  const float inv = 1.0f / (e0 + e1);
  const float a0 = e0 * inv, a1 = e1 * inv;
  float oa = a0 * bflo(v0) + a1 * bflo(v1);
  float ob = a0 * bfhi(v0) + a1 * bfhi(v1);
  oa = oa > 0.f ? oa : expm1f(oa);
  ob = ob > 0.f ? ob : expm1f(ob);
  *(float2*)(edges + e * 128 + lane * 2) = make_float2(oa, ob);
}

// One wave per node. s=16 incident edges. Writes f32 next-feats and the output slice.
__global__ __launch_bounds__(256)
void node_attn(const unsigned int* __restrict__ Qn, const unsigned int* __restrict__ Ke,
               const unsigned int* __restrict__ Ve, const int* __restrict__ n2e,
               float* __restrict__ fnext, float* __restrict__ outp) {
  const int lane = threadIdx.x & 63;
  const long n = (long)blockIdx.x * 4 + (threadIdx.x >> 6);
  const unsigned int q = Qn[n * 64 + lane];
  const float qa = bflo(q), qb = bfhi(q);
  float sc[16];
  unsigned int vv[16];
  #pragma unroll
  for (int s = 0; s < 16; ++s) {
    const long e = n2e[n * 16 + s];
    const unsigned int kk = Ke[e * 64 + lane];
    vv[s] = Ve[e * 64 + lane];
    float p = qa * bflo(kk) + qb * bfhi(kk);
    #pragma unroll
    for (int off = 1; off < 16; off <<= 1) p += __shfl_xor(p, off);
    sc[s] = p * 0.17677669529663687f;
  }
  float m = sc[0];
  #pragma unroll
  for (int s = 1; s < 16; ++s) m = fmaxf(m, sc[s]);
  float sum = 0.f;
  #pragma unroll
  for (int s = 0; s < 16; ++s) { sc[s] = __expf(sc[s] - m); sum += sc[s]; }
  const float inv = 1.0f / sum;
  float oa = 0.f, ob = 0.f;
  #pragma unroll
  for (int s = 0; s < 16; ++s) { oa += sc[s] * bflo(vv[s]); ob += sc[s] * bfhi(vv[s]); }
  oa *= inv; ob *= inv;
  oa = oa > 0.f ? oa : expm1f(oa);
  ob = ob > 0.f ? ob : expm1f(ob);
  *(float2*)(fnext + n * 128 + lane * 2) = make_float2(oa, ob);
  *(float2*)(outp + n * 256 + lane * 2) = make_float2(oa, ob);
}

extern "C" void kernel_launch(void* const* d_in, const int* in_sizes, int n_in,
                              void* d_out, int out_size, void* d_ws, size_t ws_size,
                              hipStream_t stream) {
  const float* feats     = (const float*)d_in[0];
  const float* node_emb  = (const float*)d_in[1];
  const float* Wprep     = (const float*)d_in[2];
  const float* edge_emb  = (const float*)d_in[3];
  const float* Wedgeprep = (const float*)d_in[4];
  const float* Wq_e      = (const float*)d_in[5];
  const float* Wk_e      = (const float*)d_in[6];
  const float* Wv_e      = (const float*)d_in[7];
  const float* Wq_n      = (const float*)d_in[8];
  const float* Wk_n      = (const float*)d_in[9];
  const float* Wv_n      = (const float*)d_in[10];
  const int*   n2e       = (const int*)d_in[11];
  const int*   adj       = (const int*)d_in[12];
  float* out = (float*)d_out;

  char* w = (char*)d_ws;
  auto carve = [&](size_t bytes) -> char* {
    char* p = w; w += (bytes + 255) & ~(size_t)255; return p;
  };
  float* edges = (float*)carve((size_t)E_EDGES * 128 * 4);   // 204.8 MB, in-place per layer
  float* fa    = (float*)carve((size_t)N_NODES * 128 * 4);
  float* fb    = (float*)carve((size_t)N_NODES * 128 * 4);
  unsigned int* Qe  = (unsigned int*)carve((size_t)E_EDGES * 128 * 2);
  unsigned int* KeB = (unsigned int*)carve((size_t)E_EDGES * 128 * 2);
  unsigned int* VeB = (unsigned int*)carve((size_t)E_EDGES * 128 * 2);
  unsigned int* Qn  = (unsigned int*)carve((size_t)N_NODES * 128 * 2);
  unsigned int* Kn  = (unsigned int*)carve((size_t)N_NODES * 128 * 2);
  unsigned int* Vn  = (unsigned int*)carve((size_t)N_NODES * 128 * 2);

  const int gN = (N_NODES + 63) / 64;   // 782
  const int gE = E_EDGES / 64;          // 6250

  for (int mp = 0; mp < NMPC; ++mp) {
    // prep: all_feats = feats @ Wprep ; all_edges = edge_emb[mp] @ Wedgeprep[mp]
    gemm_k<128, false, false><<<gN, 512, 0, stream>>>(feats, Wprep, fa, N_NODES);
    gemm_k<64,  false, false><<<gE, 512, 0, stream>>>(edge_emb + (size_t)mp * E_EDGES * EDIMC,
                                                      Wedgeprep + (size_t)mp * EDIMC * 128,
                                                      edges, E_EDGES);
    float* fc = fa;
    float* fn = fb;
    for (int l = 0; l < DEPTHC; ++l) {
      const size_t woff = ((size_t)mp * DEPTHC + l) * (NHEAD * DDIM * KHEAD); // 16384
      // per-entity projections (hoisted out of the gathers)
      gemm_k<128, true, true><<<gN, 512, 0, stream>>>(fc, Wk_e + woff, Kn, N_NODES);
      gemm_k<128, true, true><<<gN, 512, 0, stream>>>(fc, Wv_e + woff, Vn, N_NODES);
      gemm_k<128, true, true><<<gE, 512, 0, stream>>>(edges, Wq_e + woff, Qe, E_EDGES);
      gemm_k<128, true, true><<<gE, 512, 0, stream>>>(edges, Wk_n + woff, KeB, E_EDGES);
      gemm_k<128, true, true><<<gE, 512, 0, stream>>>(edges, Wv_n + woff, VeB, E_EDGES);
      const float* x = (l == 0) ? node_emb : (const float*)fc;
      gemm_k<128, true, true><<<gN, 512, 0, stream>>>(x, Wq_n + woff, Qn, N_NODES);
      // edge update (overwrites edges in place; old-edge K/V already extracted)
      edge_attn<<<E_EDGES / 4, 256, 0, stream>>>(Qe, Kn, Vn, adj + (size_t)mp * E_EDGES * 2, edges);
      // node update (uses OLD-edge K/V); fuses skip-output write
      node_attn<<<N_NODES / 4, 256, 0, stream>>>(Qn, KeB, VeB, n2e + (size_t)mp * N_NODES * S_NEI,
                                                 fn, out + (size_t)mp * N_NODES * 256 + (size_t)l * 128);
      float* t = fc; fc = fn; fn = t;
    }
  }
}

// Round 2
// 1703.760 us; speedup vs baseline: 2.9292x; 2.9292x over previous
//
#include <hip/hip_runtime.h>

#define N_NODES 50000
#define S_NEI 16
#define E_EDGES 400000
#define DDIM 128
#define EDIMC 64
#define NMPC 2
#define DEPTHC 2

typedef __attribute__((ext_vector_type(8))) short short8v;
typedef __attribute__((ext_vector_type(4))) float float4v;

__device__ __forceinline__ unsigned short f2bf(float f) {
  unsigned int u = __float_as_uint(f);
  unsigned int r = (u + 0x7fffu + ((u >> 16) & 1u)) >> 16;
  return (unsigned short)r;
}
__device__ __forceinline__ float bf2f(unsigned short h) { return __uint_as_float((unsigned int)h << 16); }
__device__ __forceinline__ float bflo(unsigned int u) { return __uint_as_float(u << 16); }
__device__ __forceinline__ float bfhi(unsigned int u) { return __uint_as_float(u & 0xffff0000u); }

// ---------------------------------------------------------------------------
// Weight table: 27 slots x 16384 bf16. Slot layout:
//  slots ml*6 + {0:k_e, 1:v_e, 2:q_n, 3:q_e, 4:k_n, 5:v_n}  (ml = mp*2+l), each [c=128][d=128]
//  slot 24: Wprep transposed [c=128][d=128]
//  slot 25,26: Wedgeprep[mp] transposed [c=128][k=64] (rest zero-padded)
// c = h*32 + k for attention weights.
// ---------------------------------------------------------------------------
__global__ void build_wt(const float* __restrict__ Wprep, const float* __restrict__ Wedgeprep,
                         const float* __restrict__ Wq_e, const float* __restrict__ Wk_e,
                         const float* __restrict__ Wv_e, const float* __restrict__ Wq_n,
                         const float* __restrict__ Wk_n, const float* __restrict__ Wv_n,
                         unsigned short* __restrict__ WT) {
  int idx = blockIdx.x * 256 + threadIdx.x;
  if (idx >= 27 * 16384) return;
  int slot = idx >> 14, r = idx & 16383;
  float v = 0.f;
  if (slot < 24) {
    int ml = slot / 6, mat = slot % 6;
    int c = r >> 7, d = r & 127;
    int h = c >> 5, kk = c & 31;
    const float* W = (mat == 0) ? Wk_e : (mat == 1) ? Wv_e : (mat == 2) ? Wq_n
                   : (mat == 3) ? Wq_e : (mat == 4) ? Wk_n : Wv_n;
    v = W[(((size_t)ml * 4 + h) * 128 + d) * 32 + kk];
  } else if (slot == 24) {
    int c = r >> 7, d = r & 127;
    v = Wprep[d * 128 + c];
  } else {
    int mp = slot - 25;
    int c = r >> 6, k = r & 63;
    if (c < 128) v = Wedgeprep[((size_t)mp * 64 + k) * 128 + c];
  }
  WT[idx] = f2bf(v);
}

// ---------------------------------------------------------------------------
// proj: Y_w[m][c] = bf16( X[m][:] @ W_w )  for w in 0..NW-1
//  X: hi/lo bf16 planes (ASPLIT=false) or f32 (ASPLIT=true, split in-kernel)
//  W: WT slots (consecutive), [c=128][k=KDIM] bf16, staged per-w in LDS (XOR swizzle)
//  MFMA: A-operand = W rows (c), B-operand = X rows (m) -> D[c][m]; lane stores
//  4 consecutive cols per frag as ushort4.
//  OSPLIT (NW==1): also write lo-plane Ylo.
// block = 256 thr = 4 waves; tile = 128 rows (32/wave). grid = ceil(M/128).
// ---------------------------------------------------------------------------
template<int KDIM, int NW, bool ASPLIT, bool OSPLIT>
__global__ __launch_bounds__(256, 2)
void proj(const unsigned short* __restrict__ Xhi, const unsigned short* __restrict__ Xlo,
          const float* __restrict__ Xf, const unsigned short* __restrict__ WT,
          unsigned short* __restrict__ Y0, unsigned short* __restrict__ Y1,
          unsigned short* __restrict__ Y2, unsigned short* __restrict__ Ylo, int M) {
  constexpr int NKK  = KDIM / 32;   // k-steps
  constexpr int CHPR = KDIM / 8;    // 16B chunks per W row
  constexpr int SWZ  = CHPR - 1;
  __shared__ unsigned short Wl[128 * KDIM];
  const int tid  = threadIdx.x;
  const int lane = tid & 63;
  const int wv   = tid >> 6;
  const int l15  = lane & 15, lg = lane >> 4;
  const long m0  = (long)blockIdx.x * 128 + wv * 32;

  // ---- X fragments (held across all w) ----
  short8v xh[2][NKK], xl[2][NKK];
  #pragma unroll
  for (int rf = 0; rf < 2; ++rf) {
    long row = m0 + rf * 16 + l15; if (row >= M) row = M - 1;
    #pragma unroll
    for (int kk = 0; kk < NKK; ++kk) {
      const int k0 = kk * 32 + lg * 8;
      if (ASPLIT) {
        const float* p = Xf + row * KDIM + k0;
        float4v a0 = *(const float4v*)p;
        float4v a1 = *(const float4v*)(p + 4);
        #pragma unroll
        for (int j = 0; j < 8; ++j) {
          float x = (j < 4) ? a0[j] : a1[j - 4];
          unsigned short hb = f2bf(x);
          unsigned short lb = f2bf(x - bf2f(hb));
          xh[rf][kk][j] = (short)hb;
          xl[rf][kk][j] = (short)lb;
        }
      } else {
        xh[rf][kk] = *(const short8v*)(Xhi + row * KDIM + k0);
        xl[rf][kk] = *(const short8v*)(Xlo + row * KDIM + k0);
      }
    }
  }

  unsigned short* Ys[3] = {Y0, Y1, Y2};
  #pragma unroll
  for (int w = 0; w < NW; ++w) {
    if (w) __syncthreads();  // previous W reads done before overwrite
    // stage W_w -> LDS, swizzled
    {
      const uint4* src = (const uint4*)(WT + (size_t)w * 16384);
      #pragma unroll
      for (int i = 0; i < CHPR / 2; ++i) {
        int ci = i * 256 + tid;          // chunk index, total 128*CHPR
        int row = ci / CHPR, ch = ci & SWZ;
        uint4 v = src[ci];
        *(uint4*)((char*)Wl + row * (KDIM * 2) + ((ch ^ (row & SWZ)) << 4)) = v;
      }
    }
    __syncthreads();

    float4v acc[8][2];
    #pragma unroll
    for (int cf = 0; cf < 8; ++cf)
      #pragma unroll
      for (int rf = 0; rf < 2; ++rf) acc[cf][rf] = (float4v)0.f;

    #pragma unroll
    for (int kk = 0; kk < NKK; ++kk) {
      #pragma unroll
      for (int cf = 0; cf < 8; ++cf) {
        const int row = cf * 16 + l15;
        const int ch  = (kk * 4 + lg) ^ (row & SWZ);
        short8v b = *(const short8v*)((char*)Wl + row * (KDIM * 2) + (ch << 4));
        acc[cf][0] = __builtin_amdgcn_mfma_f32_16x16x32_bf16(b, xh[0][kk], acc[cf][0], 0, 0, 0);
        acc[cf][1] = __builtin_amdgcn_mfma_f32_16x16x32_bf16(b, xh[1][kk], acc[cf][1], 0, 0, 0);
        acc[cf][0] = __builtin_amdgcn_mfma_f32_16x16x32_bf16(b, xl[0][kk], acc[cf][0], 0, 0, 0);
        acc[cf][1] = __builtin_amdgcn_mfma_f32_16x16x32_bf16(b, xl[1][kk], acc[cf][1], 0, 0, 0);
      }
    }

    #pragma unroll
    for (int rf = 0; rf < 2; ++rf) {
      const long m = m0 + rf * 16 + l15;
      if (m < M) {
        #pragma unroll
        for (int cf = 0; cf < 8; ++cf) {
          const int c0 = cf * 16 + lg * 4;
          float4v a = acc[cf][rf];
          ushort4 o;
          o.x = f2bf(a[0]); o.y = f2bf(a[1]); o.z = f2bf(a[2]); o.w = f2bf(a[3]);
          *(ushort4*)(Ys[w] + m * 128 + c0) = o;
          if (OSPLIT) {
            ushort4 ol;
            ol.x = f2bf(a[0] - bf2f(o.x)); ol.y = f2bf(a[1] - bf2f(o.y));
            ol.z = f2bf(a[2] - bf2f(o.z)); ol.w = f2bf(a[3] - bf2f(o.w));
            *(ushort4*)(Ylo + m * 128 + c0) = ol;
          }
        }
      }
    }
  }
}

// ---------------------------------------------------------------------------
// Attention kernels (Q/K/V bf16 pairs packed in u32; 2 cols per lane)
// ---------------------------------------------------------------------------
__global__ __launch_bounds__(256)
void edge_attn(const unsigned int* __restrict__ Qe, const unsigned int* __restrict__ Kn,
               const unsigned int* __restrict__ Vn, const int* __restrict__ adj,
               unsigned short* __restrict__ ehi, unsigned short* __restrict__ elo) {
  const int lane = threadIdx.x & 63;
  const long e = (long)blockIdx.x * 4 + (threadIdx.x >> 6);
  const unsigned int q = Qe[e * 64 + lane];
  const int n0 = adj[e * 2 + 0];
  const int n1 = adj[e * 2 + 1];
  const unsigned int k0 = Kn[(long)n0 * 64 + lane];
  const unsigned int k1 = Kn[(long)n1 * 64 + lane];
  const unsigned int v0 = Vn[(long)n0 * 64 + lane];
  const unsigned int v1 = Vn[(long)n1 * 64 + lane];
  const float qa = bflo(q), qb = bfhi(q);
  float p0 = qa * bflo(k0) + qb * bfhi(k0);
  float p1 = qa * bflo(k1) + qb * bfhi(k1);
  #pragma unroll
  for (int off = 1; off < 16; off <<= 1) {
    p0 += __shfl_xor(p0, off);
    p1 += __shfl_xor(p1, off);
  }
  const float scale = 0.17677669529663687f;  // 1/sqrt(32)
  const float s0 = p0 * scale, s1 = p1 * scale;
  const float m = fmaxf(s0, s1);
  const float e0 = __expf(s0 - m), e1 = __expf(s1 - m);
  const float inv = 1.0f / (e0 + e1);
  const float a0 = e0 * inv, a1 = e1 * inv;
  float oa = a0 * bflo(v0) + a1 * bflo(v1);
  float ob = a0 * bfhi(v0) + a1 * bfhi(v1);
  oa = oa > 0.f ? oa : expm1f(oa);
  ob = ob > 0.f ? ob : expm1f(ob);
  const unsigned short ha = f2bf(oa), hb = f2bf(ob);
  const unsigned short la = f2bf(oa - bf2f(ha)), lb = f2bf(ob - bf2f(hb));
  ((unsigned int*)ehi)[e * 64 + lane] = (unsigned int)ha | ((unsigned int)hb << 16);
  ((unsigned int*)elo)[e * 64 + lane] = (unsigned int)la | ((unsigned int)lb << 16);
}

__global__ __launch_bounds__(256)
void node_attn(const unsigned int* __restrict__ Qn, const unsigned int* __restrict__ Ke,
               const unsigned int* __restrict__ Ve, const int* __restrict__ n2e,
               unsigned short* __restrict__ fhi, unsigned short* __restrict__ flo,
               float* __restrict__ outp) {
  const int lane = threadIdx.x & 63;
  const long n = (long)blockIdx.x * 4 + (threadIdx.x >> 6);
  const unsigned int q = Qn[n * 64 + lane];
  const float qa = bflo(q), qb = bfhi(q);
  float sc[16];
  unsigned int vv[16];
  #pragma unroll
  for (int s = 0; s < 16; ++s) {
    const long e = n2e[n * 16 + s];
    const unsigned int kk = Ke[e * 64 + lane];
    vv[s] = Ve[e * 64 + lane];
    float p = qa * bflo(kk) + qb * bfhi(kk);
    #pragma unroll
    for (int off = 1; off < 16; off <<= 1) p += __shfl_xor(p, off);
    sc[s] = p * 0.17677669529663687f;
  }
  float m = sc[0];
  #pragma unroll
  for (int s = 1; s < 16; ++s) m = fmaxf(m, sc[s]);
  float sum = 0.f;
  #pragma unroll
  for (int s = 0; s < 16; ++s) { sc[s] = __expf(sc[s] - m); sum += sc[s]; }
  const float inv = 1.0f / sum;
  float oa = 0.f, ob = 0.f;
  #pragma unroll
  for (int s = 0; s < 16; ++s) { oa += sc[s] * bflo(vv[s]); ob += sc[s] * bfhi(vv[s]); }
  oa *= inv; ob *= inv;
  oa = oa > 0.f ? oa : expm1f(oa);
  ob = ob > 0.f ? ob : expm1f(ob);
  const unsigned short ha = f2bf(oa), hb = f2bf(ob);
  const unsigned short la = f2bf(oa - bf2f(ha)), lb = f2bf(ob - bf2f(hb));
  ((unsigned int*)fhi)[n * 64 + lane] = (unsigned int)ha | ((unsigned int)hb << 16);
  ((unsigned int*)flo)[n * 64 + lane] = (unsigned int)la | ((unsigned int)lb << 16);
  *(float2*)(outp + n * 256 + lane * 2) = make_float2(oa, ob);
}

extern "C" void kernel_launch(void* const* d_in, const int* in_sizes, int n_in,
                              void* d_out, int out_size, void* d_ws, size_t ws_size,
                              hipStream_t stream) {
  const float* feats     = (const float*)d_in[0];
  const float* node_emb  = (const float*)d_in[1];
  const float* Wprep     = (const float*)d_in[2];
  const float* edge_emb  = (const float*)d_in[3];
  const float* Wedgeprep = (const float*)d_in[4];
  const float* Wq_e      = (const float*)d_in[5];
  const float* Wk_e      = (const float*)d_in[6];
  const float* Wv_e      = (const float*)d_in[7];
  const float* Wq_n      = (const float*)d_in[8];
  const float* Wk_n      = (const float*)d_in[9];
  const float* Wv_n      = (const float*)d_in[10];
  const int*   n2e       = (const int*)d_in[11];
  const int*   adj       = (const int*)d_in[12];
  float* out = (float*)d_out;

  char* w = (char*)d_ws;
  auto carve = [&](size_t bytes) -> char* {
    char* p = w; w += (bytes + 255) & ~(size_t)255; return p;
  };
  unsigned short* ehi = (unsigned short*)carve((size_t)E_EDGES * 128 * 2);
  unsigned short* elo = (unsigned short*)carve((size_t)E_EDGES * 128 * 2);
  unsigned short* fahi = (unsigned short*)carve((size_t)N_NODES * 128 * 2);
  unsigned short* falo = (unsigned short*)carve((size_t)N_NODES * 128 * 2);
  unsigned short* fbhi = (unsigned short*)carve((size_t)N_NODES * 128 * 2);
  unsigned short* fblo = (unsigned short*)carve((size_t)N_NODES * 128 * 2);
  unsigned short* Qe  = (unsigned short*)carve((size_t)E_EDGES * 128 * 2);
  unsigned short* KeB = (unsigned short*)carve((size_t)E_EDGES * 128 * 2);
  unsigned short* VeB = (unsigned short*)carve((size_t)E_EDGES * 128 * 2);
  unsigned short* Qn  = (unsigned short*)carve((size_t)N_NODES * 128 * 2);
  unsigned short* Kn  = (unsigned short*)carve((size_t)N_NODES * 128 * 2);
  unsigned short* Vn  = (unsigned short*)carve((size_t)N_NODES * 128 * 2);
  unsigned short* WT  = (unsigned short*)carve((size_t)27 * 16384 * 2);

  build_wt<<<(27 * 16384 + 255) / 256, 256, 0, stream>>>(
      Wprep, Wedgeprep, Wq_e, Wk_e, Wv_e, Wq_n, Wk_n, Wv_n, WT);

  const int gN = (N_NODES + 127) / 128;  // 391
  const int gE = E_EDGES / 128;          // 3125

  for (int mp = 0; mp < NMPC; ++mp) {
    // prep: all_feats = feats @ Wprep ; all_edges = edge_emb[mp] @ Wedgeprep[mp]
    proj<128, 1, true, true><<<gN, 256, 0, stream>>>(
        nullptr, nullptr, feats, WT + (size_t)24 * 16384, fahi, nullptr, nullptr, falo, N_NODES);
    proj<64, 1, true, true><<<gE, 256, 0, stream>>>(
        nullptr, nullptr, edge_emb + (size_t)mp * E_EDGES * EDIMC,
        WT + (size_t)(25 + mp) * 16384, ehi, nullptr, nullptr, elo, E_EDGES);

    unsigned short *fchi = fahi, *fclo = falo, *fnhi = fbhi, *fnlo = fblo;
    for (int l = 0; l < DEPTHC; ++l) {
      const int ml = mp * 2 + l;
      const unsigned short* base = WT + (size_t)ml * 6 * 16384;
      if (l == 0) {
        proj<128, 2, false, false><<<gN, 256, 0, stream>>>(
            fchi, fclo, nullptr, base, Kn, Vn, nullptr, nullptr, N_NODES);
        proj<128, 1, true, false><<<gN, 256, 0, stream>>>(
            nullptr, nullptr, node_emb, base + (size_t)2 * 16384, Qn, nullptr, nullptr, nullptr, N_NODES);
      } else {
        proj<128, 3, false, false><<<gN, 256, 0, stream>>>(
            fchi, fclo, nullptr, base, Kn, Vn, Qn, nullptr, N_NODES);
      }
      proj<128, 3, false, false><<<gE, 256, 0, stream>>>(
          ehi, elo, nullptr, base + (size_t)3 * 16384, Qe, KeB, VeB, nullptr, E_EDGES);

      edge_attn<<<E_EDGES / 4, 256, 0, stream>>>(
          (const unsigned int*)Qe, (const unsigned int*)Kn, (const unsigned int*)Vn,
          adj + (size_t)mp * E_EDGES * 2, ehi, elo);
      node_attn<<<N_NODES / 4, 256, 0, stream>>>(
          (const unsigned int*)Qn, (const unsigned int*)KeB, (const unsigned int*)VeB,
          n2e + (size_t)mp * N_NODES * S_NEI, fnhi, fnlo,
          out + (size_t)mp * N_NODES * 256 + (size_t)l * 128);

      unsigned short* t;
      t = fchi; fchi = fnhi; fnhi = t;
      t = fclo; fclo = fnlo; fnlo = t;
    }
  }
}